// Round 1
// baseline (69.371 us; speedup 1.0000x reference)
//
#include <hip/hip_runtime.h>
#include <hip/hip_bf16.h>

#define LOG2E 1.4426950408889634f
#define C2    (2.0f * LOG2E)

static __device__ __forceinline__ float fast_exp2(float x) {
#if __has_builtin(__builtin_amdgcn_exp2f)
  return __builtin_amdgcn_exp2f(x);
#else
  return exp2f(x);
#endif
}
static __device__ __forceinline__ float fast_rcp(float x) {
#if __has_builtin(__builtin_amdgcn_rcpf)
  return __builtin_amdgcn_rcpf(x);
#else
  return 1.0f / x;
#endif
}

// ---------------------------------------------------------------------------
// Projection GEMM: Out[m][n] = C2 * sum_d X[m][d] * W[d][n]
// M = B*256 = 2048 rows, K = 256, N = 256.  bz=0: queries@W_q, bz=1: keys@W_k
// 64x64 tile per 256-thread block, 4x4 outputs/thread, K-chunks of 32.
// ---------------------------------------------------------------------------
__global__ __launch_bounds__(256) void proj_kernel(
    const float* __restrict__ queries, const float* __restrict__ keys,
    const float* __restrict__ W_q,     const float* __restrict__ W_k,
    const int*   __restrict__ vlen,
    float* __restrict__ qs, float* __restrict__ ks)
{
  const int bz = blockIdx.z;
  const float* X = bz ? keys : queries;
  const float* W = bz ? W_k  : W_q;
  float* Out     = bz ? ks   : qs;
  const int n0 = blockIdx.x * 64;
  const int m0 = blockIdx.y * 64;

  // masked keys tile: rows k >= valid_len never contribute (scores masked) —
  // skip whole 64-row tiles. Stale/poison data in the skipped rows is finite
  // (0x AAAAAAAA == -3e-13f) and gets masked to -1e6 downstream.
  if (bz == 1) {
    const int vl = vlen[m0 >> 8];
    if ((m0 & 255) >= vl) return;
  }

  const int t  = threadIdx.x;
  const int tx = t & 15, ty = t >> 4;

  __shared__ float Xs[64 * 33];
  __shared__ float Ws[32 * 68];

  float acc[4][4] = {};
  for (int kc = 0; kc < 8; ++kc) {
#pragma unroll
    for (int m = 0; m < 2; ++m) {           // stage X 64x32
      int idx = t + 256 * m;
      int row = idx >> 3, seg = idx & 7;
      float4 v = *(const float4*)&X[(m0 + row) * 256 + kc * 32 + seg * 4];
      Xs[row * 33 + seg * 4 + 0] = v.x;
      Xs[row * 33 + seg * 4 + 1] = v.y;
      Xs[row * 33 + seg * 4 + 2] = v.z;
      Xs[row * 33 + seg * 4 + 3] = v.w;
    }
#pragma unroll
    for (int m = 0; m < 2; ++m) {           // stage W 32x64
      int idx = t + 256 * m;
      int row = idx >> 4, seg = idx & 15;
      float4 v = *(const float4*)&W[(kc * 32 + row) * 256 + n0 + seg * 4];
      *(float4*)&Ws[row * 68 + seg * 4] = v;
    }
    __syncthreads();
#pragma unroll
    for (int kk = 0; kk < 32; ++kk) {
      float4 bv = *(const float4*)&Ws[kk * 68 + tx * 4];
#pragma unroll
      for (int i = 0; i < 4; ++i) {
        float a = Xs[(ty * 4 + i) * 33 + kk];
        acc[i][0] = fmaf(a, bv.x, acc[i][0]);
        acc[i][1] = fmaf(a, bv.y, acc[i][1]);
        acc[i][2] = fmaf(a, bv.z, acc[i][2]);
        acc[i][3] = fmaf(a, bv.w, acc[i][3]);
      }
    }
    __syncthreads();
  }
#pragma unroll
  for (int i = 0; i < 4; ++i) {
    float4 v = make_float4(acc[i][0] * C2, acc[i][1] * C2,
                           acc[i][2] * C2, acc[i][3] * C2);
    *(float4*)&Out[(m0 + ty * 4 + i) * 256 + n0 + tx * 4] = v;
  }
}

// ---------------------------------------------------------------------------
// Fused scores + softmax + PV.
// Grid: 256 blocks = B(8) x Qtiles(32).  Block: 512 thr = 8 waves.
// Wave ql owns q-row q0+ql; lane's k set = {lane+64j, j=0..3}.
// score[q][k] = W + sum_h w2[h] * rcp(1 + exp2(qs[q][h] + ks[k][h]))
//   with w2 = -2*w_v, W = sum(w_v), qs/ks pre-scaled by 2*log2e.
// ks staged per 32-h chunk in [h][k] layout (stride 260); values chunks reuse
// the same buffer [k][d]. Masked k-groups (k >= valid_len) skipped entirely.
// ---------------------------------------------------------------------------
__global__ __launch_bounds__(512) void attn_kernel(
    const float* __restrict__ qs, const float* __restrict__ ks,
    const float* __restrict__ values, const int* __restrict__ vlen,
    const float* __restrict__ w_v, float* __restrict__ out)
{
  const int t    = threadIdx.x;
  const int lane = t & 63;
  const int ql   = t >> 6;                 // wave id == local q row
  const int bx   = blockIdx.x;
  const int b    = bx >> 5;
  const int q0   = (bx & 31) * 8;
  const int qrow = b * 256 + q0 + ql;

  __shared__ float buf[32 * 260];          // ks chunk [h][k] / values chunk [k][d]
  __shared__ float qs_lds[8 * 256];
  __shared__ float w2_lds[256];
  __shared__ float p_lds[8 * 256];
  __shared__ float W_lds;

  // stage all 8 q-rows (scaled) + w2
  {
    float4 v = *(const float4*)&qs[qrow * 256 + lane * 4];
    *(float4*)&qs_lds[ql * 256 + lane * 4] = v;
  }
  if (t < 256) w2_lds[t] = -2.0f * w_v[t];
  __syncthreads();
  if (t < 64) {                            // W = sum w_v (wave 0)
    float s = 0.f;
#pragma unroll
    for (int i = 0; i < 4; ++i) s += w2_lds[t + 64 * i];
#pragma unroll
    for (int off = 32; off; off >>= 1) s += __shfl_xor(s, off);
    if (t == 0) W_lds = -0.5f * s;
  }
  __syncthreads();

  const int   vl = vlen[b];
  const int   nj = (vl + 63) >> 6;         // active 64-wide k groups (uniform)
  const float Wsum = W_lds;
  float sc[4] = {Wsum, Wsum, Wsum, Wsum};

  for (int hc = 0; hc < 8; ++hc) {
#pragma unroll
    for (int m = 0; m < 4; ++m) {          // stage ks chunk: [h=32][k=256]
      int idx = t + 512 * m;
      int krow = idx >> 3, seg = idx & 7;
      float4 v = *(const float4*)&ks[(b * 256 + krow) * 256 + hc * 32 + seg * 4];
      buf[(seg * 4 + 0) * 260 + krow] = v.x;
      buf[(seg * 4 + 1) * 260 + krow] = v.y;
      buf[(seg * 4 + 2) * 260 + krow] = v.z;
      buf[(seg * 4 + 3) * 260 + krow] = v.w;
    }
    __syncthreads();
#pragma unroll
    for (int h4 = 0; h4 < 8; ++h4) {
      float4 qv = *(const float4*)&qs_lds[ql * 256 + hc * 32 + h4 * 4];
      float4 wv = *(const float4*)&w2_lds[hc * 32 + h4 * 4];
      const float* r0 = &buf[(h4 * 4 + 0) * 260];
      const float* r1 = &buf[(h4 * 4 + 1) * 260];
      const float* r2 = &buf[(h4 * 4 + 2) * 260];
      const float* r3 = &buf[(h4 * 4 + 3) * 260];
#pragma unroll
      for (int j = 0; j < 4; ++j) {
        if (j < nj) {
          int k = lane + 64 * j;
          float x0 = qv.x + r0[k];
          float x1 = qv.y + r1[k];
          float x2 = qv.z + r2[k];
          float x3 = qv.w + r3[k];
          sc[j] = fmaf(wv.x, fast_rcp(fast_exp2(x0) + 1.0f), sc[j]);
          sc[j] = fmaf(wv.y, fast_rcp(fast_exp2(x1) + 1.0f), sc[j]);
          sc[j] = fmaf(wv.z, fast_rcp(fast_exp2(x2) + 1.0f), sc[j]);
          sc[j] = fmaf(wv.w, fast_rcp(fast_exp2(x3) + 1.0f), sc[j]);
        }
      }
    }
    __syncthreads();
  }

  // mask + softmax over k (row == wave)
#pragma unroll
  for (int j = 0; j < 4; ++j) {
    int k = lane + 64 * j;
    if (k >= vl) sc[j] = -1000000.0f;
  }
  float mx = fmaxf(fmaxf(sc[0], sc[1]), fmaxf(sc[2], sc[3]));
#pragma unroll
  for (int off = 32; off; off >>= 1) mx = fmaxf(mx, __shfl_xor(mx, off));
  float p[4], sum = 0.f;
#pragma unroll
  for (int j = 0; j < 4; ++j) {
    p[j] = fast_exp2((sc[j] - mx) * LOG2E);
    sum += p[j];
  }
#pragma unroll
  for (int off = 32; off; off >>= 1) sum += __shfl_xor(sum, off);
  const float inv = fast_rcp(sum);
#pragma unroll
  for (int j = 0; j < 4; ++j) p_lds[ql * 256 + lane + 64 * j] = p[j] * inv;

  // PV: out[q][d] = sum_k p[q][k] * values[b][k][d]; lane owns d = 4*lane..+3
  const int nc = (vl + 31) >> 5;           // active 32-wide k chunks (uniform)
  float4 acc = make_float4(0.f, 0.f, 0.f, 0.f);
  for (int c = 0; c < nc; ++c) {
    __syncthreads();                        // all waves done with buf
#pragma unroll
    for (int m = 0; m < 4; ++m) {          // stage values chunk [k=32][d=256]
      int idx = t + 512 * m;
      int kr = idx >> 6, seg = idx & 63;
      float4 v = *(const float4*)&values[(b * 256 + c * 32 + kr) * 256 + seg * 4];
      *(float4*)&buf[kr * 260 + seg * 4] = v;
    }
    __syncthreads();
#pragma unroll
    for (int kk = 0; kk < 32; ++kk) {
      float pk = p_lds[ql * 256 + c * 32 + kk];
      float4 v = *(const float4*)&buf[kk * 260 + lane * 4];
      acc.x = fmaf(pk, v.x, acc.x);
      acc.y = fmaf(pk, v.y, acc.y);
      acc.z = fmaf(pk, v.z, acc.z);
      acc.w = fmaf(pk, v.w, acc.w);
    }
  }
  *(float4*)&out[qrow * 256 + lane * 4] = acc;
}

extern "C" void kernel_launch(void* const* d_in, const int* in_sizes, int n_in,
                              void* d_out, int out_size, void* d_ws, size_t ws_size,
                              hipStream_t stream) {
  const float* queries = (const float*)d_in[0];
  const float* keys    = (const float*)d_in[1];
  const float* values  = (const float*)d_in[2];
  const int*   vlenp   = (const int*)d_in[3];
  const float* W_q     = (const float*)d_in[4];
  const float* W_k     = (const float*)d_in[5];
  const float* w_v     = (const float*)d_in[6];
  float* out = (float*)d_out;

  float* qs = (float*)d_ws;                 // 2048*256 f32 = 2 MiB
  float* ks = qs + 2048 * 256;              // 2048*256 f32 = 2 MiB

  dim3 pgrid(4, 32, 2);
  proj_kernel<<<pgrid, 256, 0, stream>>>(queries, keys, W_q, W_k, vlenp, qs, ks);
  attn_kernel<<<256, 512, 0, stream>>>(qs, ks, values, vlenp, w_v, out);
}

// Round 2
// 53.429 us; speedup vs baseline: 1.2984x; 1.2984x over previous
//
#include <hip/hip_runtime.h>
#include <hip/hip_bf16.h>

#define LOG2E 1.4426950408889634f
#define C2    (2.0f * LOG2E)

static __device__ __forceinline__ float fast_exp2(float x) {
#if __has_builtin(__builtin_amdgcn_exp2f)
  return __builtin_amdgcn_exp2f(x);
#else
  return exp2f(x);
#endif
}
static __device__ __forceinline__ float fast_rcp(float x) {
#if __has_builtin(__builtin_amdgcn_rcpf)
  return __builtin_amdgcn_rcpf(x);
#else
  return 1.0f / x;
#endif
}

// ---------------------------------------------------------------------------
// Projection GEMM: Out[m][n] = C2 * sum_d X[m][d] * W[d][n]
// M = 2048, K = 256, N = 256.  bz=0: queries@W_q, bz=1: keys@W_k
// 32x64 tile, 256 threads, 2x4 outputs/thread, K-chunks of 32.
// Xs stored transposed [k][row] so the A operand is one float2 read.
// Grid 512 blocks -> 2 blocks/CU -> 2 waves/SIMD (was 1).
// ---------------------------------------------------------------------------
__global__ __launch_bounds__(256) void proj_kernel(
    const float* __restrict__ queries, const float* __restrict__ keys,
    const float* __restrict__ W_q,     const float* __restrict__ W_k,
    const int*   __restrict__ vlen,
    float* __restrict__ qs, float* __restrict__ ks)
{
  const int bz = blockIdx.z;
  const float* X = bz ? keys : queries;
  const float* W = bz ? W_k  : W_q;
  float* Out     = bz ? ks   : qs;
  const int n0 = blockIdx.x * 64;
  const int m0 = blockIdx.y * 32;

  // keys rows k >= valid_len are masked downstream — skip whole tiles.
  if (bz == 1) {
    const int vl = vlen[m0 >> 8];
    if ((m0 & 255) >= vl) return;
  }

  const int t  = threadIdx.x;
  const int tx = t & 15, ty = t >> 4;

  __shared__ float Xs[32 * 34];   // [k][row], pad 34 (even -> aligned b64)
  __shared__ float Ws[32 * 68];   // [k][n],  pad 68

  float4 acc0 = make_float4(0.f, 0.f, 0.f, 0.f);
  float4 acc1 = make_float4(0.f, 0.f, 0.f, 0.f);

  for (int kc = 0; kc < 8; ++kc) {
    {                                       // stage X 32x32 transposed
      int row = t >> 3, seg = t & 7;
      float4 v = *(const float4*)&X[(m0 + row) * 256 + kc * 32 + seg * 4];
      Xs[(seg * 4 + 0) * 34 + row] = v.x;
      Xs[(seg * 4 + 1) * 34 + row] = v.y;
      Xs[(seg * 4 + 2) * 34 + row] = v.z;
      Xs[(seg * 4 + 3) * 34 + row] = v.w;
    }
#pragma unroll
    for (int m = 0; m < 2; ++m) {           // stage W 32x64
      int idx = t + 256 * m;
      int row = idx >> 4, seg = idx & 15;
      *(float4*)&Ws[row * 68 + seg * 4] =
          *(const float4*)&W[(kc * 32 + row) * 256 + n0 + seg * 4];
    }
    __syncthreads();
#pragma unroll
    for (int kk = 0; kk < 32; ++kk) {
      float2 a  = *(const float2*)&Xs[kk * 34 + ty * 2];
      float4 bv = *(const float4*)&Ws[kk * 68 + tx * 4];
      acc0.x = fmaf(a.x, bv.x, acc0.x);
      acc0.y = fmaf(a.x, bv.y, acc0.y);
      acc0.z = fmaf(a.x, bv.z, acc0.z);
      acc0.w = fmaf(a.x, bv.w, acc0.w);
      acc1.x = fmaf(a.y, bv.x, acc1.x);
      acc1.y = fmaf(a.y, bv.y, acc1.y);
      acc1.z = fmaf(a.y, bv.z, acc1.z);
      acc1.w = fmaf(a.y, bv.w, acc1.w);
    }
    __syncthreads();
  }
  float4 o0 = make_float4(acc0.x * C2, acc0.y * C2, acc0.z * C2, acc0.w * C2);
  float4 o1 = make_float4(acc1.x * C2, acc1.y * C2, acc1.z * C2, acc1.w * C2);
  *(float4*)&Out[(m0 + ty * 2 + 0) * 256 + n0 + tx * 4] = o0;
  *(float4*)&Out[(m0 + ty * 2 + 1) * 256 + n0 + tx * 4] = o1;
}

// ---------------------------------------------------------------------------
// Fused scores + softmax + PV.
// Grid: 1024 blocks = B(8) x Qtiles(128).  Block: 512 thr = 8 waves
//   = 2 q-rows x 4 k-groups.  Wave (ql,kg): lane's k = kg*64 + lane (ONE k).
// score[q][k] = W + sum_h w2[h] * rcp(1 + exp2(qs[q][h] + ks[k][h]))
// ks staged per 16-h chunk in [h][k] LDS layout.  Softmax + PV reduced
// across the 4 k-group waves via LDS.  PV reads V straight from L2
// (coalesced float4), no LDS staging.  LDS ~30 KB -> 4 blocks/CU,
// launch_bounds(512,8) -> 32 waves/CU.
// ---------------------------------------------------------------------------
__global__ __launch_bounds__(512, 8) void attn_kernel(
    const float* __restrict__ qs, const float* __restrict__ ks,
    const float* __restrict__ values, const int* __restrict__ vlen,
    const float* __restrict__ w_v, float* __restrict__ out)
{
  const int t    = threadIdx.x;
  const int lane = t & 63;
  const int w    = t >> 6;
  const int ql   = w >> 2;                 // 0..1
  const int kg   = w & 3;                  // 0..3
  const int bx   = blockIdx.x;
  const int b    = bx >> 7;
  const int q0   = (bx & 127) * 2;

  __shared__ float buf[16 * 260];          // ks chunk [h=16][k=256]
  __shared__ float qs_lds[2 * 256];
  __shared__ float w2_lds[256];
  __shared__ float p_lds[2 * 256];
  __shared__ float part[2][4][256];        // per-(q,kg) PV partials
  __shared__ float red_max[2][4];
  __shared__ float red_sum[2][4];

  // stage 2 q-rows + w2
  if (t < 128) {
    int q = t >> 6, seg = t & 63;
    *(float4*)&qs_lds[q * 256 + seg * 4] =
        *(const float4*)&qs[(b * 256 + q0 + q) * 256 + seg * 4];
  }
  if (t < 256) w2_lds[t] = -2.0f * w_v[t];
  __syncthreads();

  // every wave redundantly computes W = -0.5 * sum(w2)
  float s0 = w2_lds[lane] + w2_lds[lane + 64] + w2_lds[lane + 128] + w2_lds[lane + 192];
#pragma unroll
  for (int off = 32; off; off >>= 1) s0 += __shfl_xor(s0, off);
  const float Wsum = -0.5f * s0;

  const int vl   = vlen[b];
  const int nj   = (vl + 63) >> 6;         // active k-groups
  const int njk  = nj * 64;                // staged k bound
  const int kloc = kg * 64 + lane;

  float sc = Wsum;
  for (int hc = 0; hc < 16; ++hc) {
#pragma unroll
    for (int m = 0; m < 2; ++m) {          // stage ks chunk transposed
      int idx = t + 512 * m;
      int krow = idx >> 2, seg = idx & 3;
      if (krow < njk) {
        float4 v = *(const float4*)&ks[(b * 256 + krow) * 256 + hc * 16 + seg * 4];
        buf[(seg * 4 + 0) * 260 + krow] = v.x;
        buf[(seg * 4 + 1) * 260 + krow] = v.y;
        buf[(seg * 4 + 2) * 260 + krow] = v.z;
        buf[(seg * 4 + 3) * 260 + krow] = v.w;
      }
    }
    __syncthreads();
    if (kg < nj) {
#pragma unroll
      for (int h4 = 0; h4 < 4; ++h4) {
        float4 qv = *(const float4*)&qs_lds[ql * 256 + hc * 16 + h4 * 4];
        float4 wv = *(const float4*)&w2_lds[hc * 16 + h4 * 4];
        float x0 = qv.x + buf[(h4 * 4 + 0) * 260 + kloc];
        float x1 = qv.y + buf[(h4 * 4 + 1) * 260 + kloc];
        float x2 = qv.z + buf[(h4 * 4 + 2) * 260 + kloc];
        float x3 = qv.w + buf[(h4 * 4 + 3) * 260 + kloc];
        sc = fmaf(wv.x, fast_rcp(fast_exp2(x0) + 1.0f), sc);
        sc = fmaf(wv.y, fast_rcp(fast_exp2(x1) + 1.0f), sc);
        sc = fmaf(wv.z, fast_rcp(fast_exp2(x2) + 1.0f), sc);
        sc = fmaf(wv.w, fast_rcp(fast_exp2(x3) + 1.0f), sc);
      }
    }
    __syncthreads();
  }

  // mask + cross-wave softmax (4 waves per q-row)
  if (kloc >= vl) sc = -1000000.0f;
  float mx = sc;
#pragma unroll
  for (int off = 32; off; off >>= 1) mx = fmaxf(mx, __shfl_xor(mx, off));
  if (lane == 0) red_max[ql][kg] = mx;
  __syncthreads();
  mx = fmaxf(fmaxf(red_max[ql][0], red_max[ql][1]),
             fmaxf(red_max[ql][2], red_max[ql][3]));
  float p = fast_exp2((sc - mx) * LOG2E);  // 0 for masked lanes
  p_lds[ql * 256 + kloc] = p;
  float ps = p;
#pragma unroll
  for (int off = 32; off; off >>= 1) ps += __shfl_xor(ps, off);
  if (lane == 0) red_sum[ql][kg] = ps;
  __syncthreads();

  // PV partial: wave (ql,kg) covers k in [kg*64, kg*64+nk), d = 4*lane..+3
  const int nk = min(64, vl - kg * 64);    // may be <= 0 (inactive wave)
  float4 acc = make_float4(0.f, 0.f, 0.f, 0.f);
  const float* Vp = values + (b * 256 + kg * 64) * 256 + lane * 4;
  const float* pp = &p_lds[ql * 256 + kg * 64];
#pragma unroll 4
  for (int kk = 0; kk < nk; ++kk) {
    float pk = pp[kk];
    float4 v = *(const float4*)(Vp + kk * 256);
    acc.x = fmaf(pk, v.x, acc.x);
    acc.y = fmaf(pk, v.y, acc.y);
    acc.z = fmaf(pk, v.z, acc.z);
    acc.w = fmaf(pk, v.w, acc.w);
  }
  *(float4*)&part[ql][kg][lane * 4] = acc;
  __syncthreads();

  // final reduce: 512 threads = 2 q-rows x 256 d
  {
    int q = t >> 8, d = t & 255;
    float ssum = red_sum[q][0] + red_sum[q][1] + red_sum[q][2] + red_sum[q][3];
    float o = (part[q][0][d] + part[q][1][d] + part[q][2][d] + part[q][3][d]) *
              fast_rcp(ssum);
    out[(b * 256 + q0 + q) * 256 + d] = o;
  }
}

extern "C" void kernel_launch(void* const* d_in, const int* in_sizes, int n_in,
                              void* d_out, int out_size, void* d_ws, size_t ws_size,
                              hipStream_t stream) {
  const float* queries = (const float*)d_in[0];
  const float* keys    = (const float*)d_in[1];
  const float* values  = (const float*)d_in[2];
  const int*   vlenp   = (const int*)d_in[3];
  const float* W_q     = (const float*)d_in[4];
  const float* W_k     = (const float*)d_in[5];
  const float* w_v     = (const float*)d_in[6];
  float* out = (float*)d_out;

  float* qs = (float*)d_ws;                 // 2048*256 f32 = 2 MiB
  float* ks = qs + 2048 * 256;              // 2048*256 f32 = 2 MiB

  dim3 pgrid(4, 64, 2);
  proj_kernel<<<pgrid, 256, 0, stream>>>(queries, keys, W_q, W_k, vlenp, qs, ks);
  attn_kernel<<<1024, 512, 0, stream>>>(qs, ks, values, vlenp, w_v, out);
}